// Round 12
// baseline (1771.661 us; speedup 1.0000x reference)
//
#include <hip/hip_runtime.h>

// LSTM: VOCAB=50000, EMBED=50, NFEAT=3, T=120, HIDDEN=300, NCLASS=5, BATCH=1024
// R12: R8/R10-PROVEN sync protocol (plain h stores -> vmcnt(0) -> barrier ->
// tid0 AGENT fetch_add; consumer tid0 AGENT relaxed poll -> barrier ->
// buffer_inv -> plain L2 loads), retiled to 512 thr / 8 waves so ALL weight
// fragments fit in arch VGPRs (no AGPR shuffling / L2 re-stream):
//   wave (wm, gp, uh): M=16 rows, N=32 cols (2 gates x 16 units), K=320.
//   bh=80 + bx=40 + va=40 + acc=16 regs/thread ~= 230 < 256 cap.
// Gate fusion via z_lds (32KB); c-state 4/thread. Flags init via atomic-store
// kernel (no memset dirty-line hazard). XCC_ID placement (proven R6/R8).

#define BATCH 1024
#define TT    120
#define HID   300
#define KX    160
#define KH    320   // 5 slices * 64
#define SL    64
#define HSL   60
#define NCOL  1280  // 5 slices * 256 packed gate columns
#define GH    5
#define GB    32
#define BS    32
#define XST   168   // x_lds row stride in shorts
#define FSTR  32    // flag stride in ints (128B)
#define NSLOT 3
#define NB    256
#define THR   512

typedef __attribute__((ext_vector_type(8))) short bf16x8;
typedef __attribute__((ext_vector_type(4))) float f32x4;

__device__ __forceinline__ unsigned short f2b(float f) {
  union { float f; unsigned u; } v; v.f = f;
  unsigned r = v.u + 0x7fffu + ((v.u >> 16) & 1u);
  return (unsigned short)(r >> 16);
}
__device__ __forceinline__ float sigm(float x) {
  return __builtin_amdgcn_rcpf(1.f + __expf(-x));
}
__device__ __forceinline__ float tanhf_(float x) {
  return 2.f * __builtin_amdgcn_rcpf(1.f + __expf(-2.f * x)) - 1.f;
}

// column map: c in [0,1280): j=c>>8, r=c&255, g=r>>6, u0=r&63; valid u0<60
__global__ void k_reorder_wh(const float* __restrict__ W, unsigned short* __restrict__ Wp) {
  int tid = blockIdx.x * 256 + threadIdx.x;
  if (tid >= KH * NCOL) return;
  int c = tid % NCOL, k = tid / NCOL;
  int js = k >> 6, v0 = k & 63;
  int j = c >> 8, r = c & 255, g = r >> 6, u0 = r & 63;
  float val = 0.f;
  if (v0 < HSL && u0 < HSL) val = W[(js * HSL + v0) * 1200 + g * 300 + j * HSL + u0];
  Wp[((k >> 3) * NCOL + c) * 8 + (k & 7)] = f2b(val);
}

__global__ void k_reorder_wx(const float* __restrict__ W, unsigned short* __restrict__ Wp) {
  int tid = blockIdx.x * 256 + threadIdx.x;
  if (tid >= KX * NCOL) return;
  int c = tid % NCOL, k = tid / NCOL;
  int j = c >> 8, r = c & 255, g = r >> 6, u0 = r & 63;
  float val = 0.f;
  if (k < 150 && u0 < HSL) val = W[k * 1200 + g * 300 + j * HSL + u0];
  Wp[((k >> 3) * NCOL + c) * 8 + (k & 7)] = f2b(val);
}

__global__ void k_reorder_b(const float* __restrict__ b, float* __restrict__ bp) {
  int c = blockIdx.x * 256 + threadIdx.x;
  if (c >= NCOL) return;
  int j = c >> 8, r = c & 255, g = r >> 6, u0 = r & 63;
  bp[c] = (u0 < HSL) ? b[g * 300 + j * HSL + u0] : 0.f;
}

__global__ void k_reorder_u(const float* __restrict__ U, unsigned short* __restrict__ Up) {
  int tid = blockIdx.x * 256 + threadIdx.x;
  if (tid >= KH * 16) return;
  int n = tid % 16, k = tid / 16;
  int js = k >> 6, v0 = k & 63;
  float v = (v0 < HSL && n < 5) ? U[(js * HSL + v0) * 5 + n] : 0.f;
  Up[((k >> 3) * 16 + n) * 8 + (k & 7)] = f2b(v);
}

// atomic-store init: flags/xcd_cnt land at the coherent point (no dirty-L2 lines)
__global__ void k_init(int* __restrict__ flags, int n, int* __restrict__ xcd_cnt) {
  int i = blockIdx.x * 256 + threadIdx.x;
  if (i < n)
    __hip_atomic_store(flags + i, 0, __ATOMIC_RELAXED, __HIP_MEMORY_SCOPE_AGENT);
  if (i < 8)
    __hip_atomic_store(xcd_cnt + i, 0, __ATOMIC_RELAXED, __HIP_MEMORY_SCOPE_AGENT);
}

__launch_bounds__(THR, 2)
__global__ void k_lstm(const int* __restrict__ ids, const float* __restrict__ embed,
                       const unsigned short* __restrict__ Wp,
                       const unsigned short* __restrict__ Wxp,
                       const float* __restrict__ bp,
                       const unsigned short* __restrict__ Up,
                       unsigned short* __restrict__ hbuf,   // [3][1024][320] bf16
                       int* __restrict__ flags,             // [120][32] @128B counters
                       int* __restrict__ xcd_cnt,           // [8]
                       const float* __restrict__ b2,
                       float* __restrict__ out) {
  __shared__ __align__(16) unsigned short x_lds[2][BS * XST];
  __shared__ __align__(16) float z_lds[BS * 4 * SL];   // [row][gate][unit] 32KB
  __shared__ char lds_pad[61440];                      // force 1 block/CU
  __shared__ int role[2];

  const int tid = threadIdx.x;
  if (tid == 0) {
    ((volatile char*)lds_pad)[0] = 0;
    int xcd = __builtin_amdgcn_s_getreg(63508) & 7;  // HW_REG_XCC_ID
    int rank = atomicAdd(&xcd_cnt[xcd], 1);
    role[0] = xcd; role[1] = rank;
  }
  __syncthreads();
  const int xcd = role[0], rank = role[1];
  if (rank >= GH * 4) return;               // spare block
  const int bg = xcd * 4 + rank / GH;
  const int j  = rank % GH;

  const int lane = tid & 63, w = tid >> 6;  // 8 waves
  const int wm = w >> 2;                    // M half: rows wm*16..+15
  const int gp = (w >> 1) & 1;              // gate pair: gates 2gp, 2gp+1
  const int uh = w & 1;                     // unit half: units uh*32..+31
  const int l15 = lane & 15, l4 = lane >> 4;

  if (tid < BS) {
#pragma unroll
    for (int bq = 0; bq < 2; ++bq)
      for (int e = 150; e < XST; ++e) x_lds[bq][tid * XST + e] = 0;
  }

  // B-frags: gf = gidx*2+nt -> col = j*256 + (2gp+gidx)*64 + uh*32 + nt*16 + l15
  bf16x8 bh[10][4], bx[5][4];
#pragma unroll
  for (int kk = 0; kk < 10; ++kk)
#pragma unroll
    for (int gf = 0; gf < 4; ++gf) {
      int col = j * 256 + (2 * gp + (gf >> 1)) * 64 + uh * 32 + (gf & 1) * 16 + l15;
      bh[kk][gf] = *(const bf16x8*)(Wp + ((kk * 4 + l4) * NCOL + col) * 8);
    }
#pragma unroll
  for (int kk = 0; kk < 5; ++kk)
#pragma unroll
    for (int gf = 0; gf < 4; ++gf) {
      int col = j * 256 + (2 * gp + (gf >> 1)) * 64 + uh * 32 + (gf & 1) * 16 + l15;
      bx[kk][gf] = *(const bf16x8*)(Wxp + ((kk * 4 + l4) * NCOL + col) * 8);
    }

  // gates-phase geometry: thread owns (row = tid>>4, units 4*(tid&15)..+3)
  const int grow = tid >> 4, gup = tid & 15;
  float bias[4][4];   // [gate][i]
#pragma unroll
  for (int g = 0; g < 4; ++g)
#pragma unroll
    for (int i = 0; i < 4; ++i)
      bias[g][i] = bp[j * 256 + g * 64 + gup * 4 + i];
  const float b2v = (l15 < 5) ? b2[l15] : 0.f;

  // x-gather geometry (tid<192)
  int xrow = 0, koff = 0, nf2 = 0, f = 0;
  const bool gth = (tid < 192);
  if (gth) {
    xrow = tid / 6; int half = tid % 6; f = half >> 1; int hh = half & 1;
    nf2 = hh ? 12 : 13;
    koff = f * 50 + (hh ? 26 : 0);
  }
  const long idbase = (long)(bg * BS + xrow) * TT * 3 + f;
  const int  eoff   = (koff - f * 50);

  // prologue: x(0) gather+pack
  if (gth) {
    int id0 = ids[idbase + 0 * 3];
    const float* src = embed + (long)id0 * 50 + eoff;
    unsigned short* dst = &x_lds[0][xrow * XST + koff];
#pragma unroll
    for (int e = 0; e < 13; ++e)
      if (e < nf2) {
        float2 v = *(const float2*)(src + 2 * e);
        *(unsigned*)(dst + 2 * e) = (unsigned)f2b(v.x) | ((unsigned)f2b(v.y) << 16);
      }
  }
  __syncthreads();

  f32x4 acc[4];
  float cst[4];
#pragma unroll
  for (int gf = 0; gf < 4; ++gf) acc[gf] = {0.f, 0.f, 0.f, 0.f};
#pragma unroll
  for (int i = 0; i < 4; ++i) cst[i] = 0.f;

  // GEMM1(0)
  {
    const unsigned short* xb = &x_lds[0][(wm * 16 + l15) * XST + l4 * 8];
#pragma unroll
    for (int kk = 0; kk < 5; ++kk) {
      bf16x8 a = *(const bf16x8*)(xb + kk * 32);
#pragma unroll
      for (int gf = 0; gf < 4; ++gf)
        acc[gf] = __builtin_amdgcn_mfma_f32_16x16x32_bf16(a, bx[kk][gf], acc[gf], 0, 0, 0);
    }
  }

  // pipeline regs
  float2 xv[13];
  int idv = 0;
  if (gth) {
    int id1 = ids[idbase + 1 * 3];
    const float* src = embed + (long)id1 * 50 + eoff;
#pragma unroll
    for (int e = 0; e < 13; ++e)
      if (e < nf2) xv[e] = *(const float2*)(src + 2 * e);
    idv = ids[idbase + 2 * 3];
  }

  bf16x8 va[10];

  for (int t = 0; t < TT; ++t) {
    if (t > 0) {
      if (tid == 0) {  // R8-proven relaxed AGENT poll
        int* fp = flags + ((t - 1) * GB + bg) * FSTR;
        int it = 0;
        while (__hip_atomic_load(fp, __ATOMIC_RELAXED, __HIP_MEMORY_SCOPE_AGENT) < GH) {
          __builtin_amdgcn_s_sleep(1);
          if (++it > 200000) break;  // bail -> wrong answer, not a hang
        }
      }
      __syncthreads();
      // drop stale L1; partners' h is in this XCD's L2 (R8-proven path)
      asm volatile("buffer_inv\n\ts_waitcnt vmcnt(0)" ::: "memory");

      const unsigned short* ar =
          hbuf + ((t - 1) % NSLOT) * (BATCH * KH) + (bg * BS + wm * 16 + l15) * KH + l4 * 8;
#pragma unroll
      for (int kk = 0; kk < 10; ++kk)
        va[kk] = *(const bf16x8*)(ar + kk * 32);
#pragma unroll
      for (int kk = 0; kk < 10; ++kk)
#pragma unroll
        for (int gf = 0; gf < 4; ++gf)
          acc[gf] = __builtin_amdgcn_mfma_f32_16x16x32_bf16(va[kk], bh[kk][gf], acc[gf], 0, 0, 0);
    }

    // write z tiles to LDS: row=wm*16+l4*4+r, gate=2gp+(gf>>1), unit=uh*32+(gf&1)*16+l15
#pragma unroll
    for (int gf = 0; gf < 4; ++gf) {
      int gate = 2 * gp + (gf >> 1);
      int uu = uh * 32 + (gf & 1) * 16 + l15;
#pragma unroll
      for (int r = 0; r < 4; ++r)
        z_lds[(wm * 16 + l4 * 4 + r) * 256 + gate * 64 + uu] = acc[gf][r];
      acc[gf] = {0.f, 0.f, 0.f, 0.f};
    }
    __syncthreads();

    // gates + state update: 4 (row,unit) per thread; h(t) 8B plain store -> L2
    {
      const float* zr = z_lds + grow * 256 + gup * 4;
      unsigned short hsv[4];
#pragma unroll
      for (int i = 0; i < 4; ++i) {
        float zi = zr[0 * 64 + i] + bias[0][i];
        float zf = zr[1 * 64 + i] + bias[1][i];
        float zg = zr[2 * 64 + i] + bias[2][i];
        float zo = zr[3 * 64 + i] + bias[3][i];
        float gi = sigm(zi), gf_ = sigm(zf), go = sigm(zo), gg = tanhf_(zg);
        float c = gf_ * cst[i] + gi * gg;
        cst[i] = c;
        hsv[i] = f2b(go * tanhf_(c));
      }
      unsigned long long p2 =
          (unsigned long long)((unsigned)hsv[0] | ((unsigned)hsv[1] << 16)) |
          ((unsigned long long)((unsigned)hsv[2] | ((unsigned)hsv[3] << 16)) << 32);
      unsigned short* hdst = hbuf + (t % NSLOT) * (BATCH * KH);
      *(unsigned long long*)(hdst + (bg * BS + grow) * KH + j * SL + gup * 4) = p2;
    }

    // release: all h stores L2-acked, then one AGENT fetch_add (R8-proven)
    asm volatile("s_waitcnt vmcnt(0)" ::: "memory");
    __syncthreads();
    if (tid == 0)
      __hip_atomic_fetch_add(flags + (t * GB + bg) * FSTR, 1, __ATOMIC_RELAXED,
                             __HIP_MEMORY_SCOPE_AGENT);

    // y(t-1) duty from register va (waves 0 and 4; post-release, off chain)
    if (t > 0 && j == (t - 1) % GH && (w & 3) == 0) {
      f32x4 ay = {0.f, 0.f, 0.f, 0.f};
#pragma unroll
      for (int kk = 0; kk < 10; ++kk) {
        bf16x8 u = *(const bf16x8*)(Up + ((kk * 4 + l4) * 16 + l15) * 8);
        ay = __builtin_amdgcn_mfma_f32_16x16x32_bf16(va[kk], u, ay, 0, 0, 0);
      }
      if (l15 < 5)
#pragma unroll
        for (int q = 0; q < 4; ++q)
          out[((bg * BS + wm * 16 + l4 * 4 + q) * TT + (t - 1)) * 5 + l15] = ay[q] + b2v;
    }

    // tail: pack x(t+1); GEMM1(t+1); refill pipeline
    if (t + 1 < TT) {
      if (gth) {
        unsigned short* dst = &x_lds[(t + 1) & 1][xrow * XST + koff];
#pragma unroll
        for (int e = 0; e < 13; ++e)
          if (e < nf2)
            *(unsigned*)(dst + 2 * e) = (unsigned)f2b(xv[e].x) | ((unsigned)f2b(xv[e].y) << 16);
      }
      __syncthreads();
      const unsigned short* xb = &x_lds[(t + 1) & 1][(wm * 16 + l15) * XST + l4 * 8];
#pragma unroll
      for (int kk = 0; kk < 5; ++kk) {
        bf16x8 a = *(const bf16x8*)(xb + kk * 32);
#pragma unroll
        for (int gf = 0; gf < 4; ++gf)
          acc[gf] = __builtin_amdgcn_mfma_f32_16x16x32_bf16(a, bx[kk][gf], acc[gf], 0, 0, 0);
      }
      if (gth && t + 2 < TT) {
        const float* src = embed + (long)idv * 50 + eoff;
#pragma unroll
        for (int e = 0; e < 13; ++e)
          if (e < nf2) xv[e] = *(const float2*)(src + 2 * e);
        if (t + 3 < TT) idv = ids[idbase + (long)(t + 3) * 3];
      }
    }
  }

  // epilogue: y(119) by slice 4, waves 0/4
  if (j == (TT - 1) % GH) {
    if (tid == 0) {
      int* fp = flags + ((TT - 1) * GB + bg) * FSTR;
      int it = 0;
      while (__hip_atomic_load(fp, __ATOMIC_RELAXED, __HIP_MEMORY_SCOPE_AGENT) < GH) {
        __builtin_amdgcn_s_sleep(1);
        if (++it > 200000) break;
      }
    }
    __syncthreads();
    asm volatile("buffer_inv\n\ts_waitcnt vmcnt(0)" ::: "memory");
    if ((w & 3) == 0) {
      const unsigned short* ar =
          hbuf + ((TT - 1) % NSLOT) * (BATCH * KH) + (bg * BS + wm * 16 + l15) * KH + l4 * 8;
#pragma unroll
      for (int kk = 0; kk < 10; ++kk)
        va[kk] = *(const bf16x8*)(ar + kk * 32);
      f32x4 ay = {0.f, 0.f, 0.f, 0.f};
#pragma unroll
      for (int kk = 0; kk < 10; ++kk) {
        bf16x8 u = *(const bf16x8*)(Up + ((kk * 4 + l4) * 16 + l15) * 8);
        ay = __builtin_amdgcn_mfma_f32_16x16x32_bf16(va[kk], u, ay, 0, 0, 0);
      }
      if (l15 < 5)
#pragma unroll
        for (int q = 0; q < 4; ++q)
          out[((bg * BS + wm * 16 + l4 * 4 + q) * TT + (TT - 1)) * 5 + l15] = ay[q] + b2v;
    }
  }
}

extern "C" void kernel_launch(void* const* d_in, const int* in_sizes, int n_in,
                              void* d_out, int out_size, void* d_ws, size_t ws_size,
                              hipStream_t stream) {
  const int*   ids   = (const int*)d_in[0];
  const float* embed = (const float*)d_in[1];
  const float* Wx    = (const float*)d_in[2];
  const float* Wh    = (const float*)d_in[3];
  const float* b     = (const float*)d_in[4];
  const float* U     = (const float*)d_in[5];
  const float* b2    = (const float*)d_in[6];
  float* out = (float*)d_out;

  char* ws = (char*)d_ws;
  size_t off = 0;
  unsigned short* Wp   = (unsigned short*)(ws + off); off += (size_t)KH * NCOL * 2;
  unsigned short* Wxp  = (unsigned short*)(ws + off); off += (size_t)KX * NCOL * 2;
  float*          bp   = (float*)(ws + off);          off += (size_t)NCOL * 4;
  unsigned short* Up   = (unsigned short*)(ws + off); off += (size_t)KH * 16 * 2;
  unsigned short* hbuf = (unsigned short*)(ws + off); off += (size_t)NSLOT * BATCH * KH * 2;
  int*            flags= (int*)(ws + off);            off += (size_t)TT * GB * FSTR * 4;
  int*            xcd_cnt = (int*)(ws + off);         off += 8 * 4;
  if (ws_size < off) return;  // ~3.7 MB required

  k_init<<<(TT * GB * FSTR + 255) / 256, 256, 0, stream>>>(flags, TT * GB * FSTR, xcd_cnt);
  k_reorder_wh<<<(KH * NCOL + 255) / 256, 256, 0, stream>>>(Wh, Wp);
  k_reorder_wx<<<(KX * NCOL + 255) / 256, 256, 0, stream>>>(Wx, Wxp);
  k_reorder_b<<<(NCOL + 255) / 256, 256, 0, stream>>>(b, bp);
  k_reorder_u<<<(KH * 16 + 255) / 256, 256, 0, stream>>>(U, Up);

  k_lstm<<<dim3(NB), dim3(THR), 0, stream>>>(ids, embed, Wp, Wxp, bp, Up,
                                             hbuf, flags, xcd_cnt, b2, out);
}

// Round 13
// 671.867 us; speedup vs baseline: 2.6369x; 2.6369x over previous
//
#include <hip/hip_runtime.h>

// LSTM: VOCAB=50000, EMBED=50, NFEAT=3, T=120, HIDDEN=300, NCLASS=5, BATCH=1024
// R13 = R10 (proven 712us: XCD-local h exchange, AGENT-atomic flags, 256thr)
// + AGPR-resident weights: GEMM MFMAs via inline asm with "a" constraint on
//   the B operand -> bh(160)+bx(80) regs live in the otherwise-idle AGPR half
//   of the unified file; arch-VGPR pressure drops ~390->~180, killing the
//   per-step L2 weight re-stream on the MFMA critical path.
// + poll by lane0-of-each-wave (4 pollers/block, not 256).

#define BATCH 1024
#define TT    120
#define HID   300
#define KX    160
#define KH    320   // 5 slices * 64
#define SL    64
#define HSL   60
#define NCOL  1280  // 5 slices * 256 packed gate columns
#define GH    5
#define GB    32
#define BS    32
#define XST   168   // x_lds row stride in shorts
#define FSTR  32    // flag stride in ints (128B)
#define NSLOT 3
#define NB    256
#define NREL  (GH * 4)   // releases per (t,bg): 5 slices x 4 waves

typedef __attribute__((ext_vector_type(8))) short bf16x8;
typedef __attribute__((ext_vector_type(4))) float f32x4;

__device__ __forceinline__ unsigned short f2b(float f) {
  union { float f; unsigned u; } v; v.f = f;
  unsigned r = v.u + 0x7fffu + ((v.u >> 16) & 1u);
  return (unsigned short)(r >> 16);
}
__device__ __forceinline__ float sigm(float x) {
  return __builtin_amdgcn_rcpf(1.f + __expf(-x));
}
__device__ __forceinline__ float tanhf_(float x) {
  return 2.f * __builtin_amdgcn_rcpf(1.f + __expf(-2.f * x)) - 1.f;
}
// MFMA with B operand pinned to AGPRs ("a" constraint): weights stay resident
// in the unified file's acc half, off the arch-VGPR budget and off L2.
__device__ __forceinline__ void mfma_bA(bf16x8 a, const bf16x8& b, f32x4& c) {
  asm("v_mfma_f32_16x16x32_bf16 %0, %1, %2, %0" : "+v"(c) : "v"(a), "a"(b));
}

__global__ void k_reorder_wh(const float* __restrict__ W, unsigned short* __restrict__ Wp) {
  int tid = blockIdx.x * 256 + threadIdx.x;
  if (tid >= KH * NCOL) return;
  int c = tid % NCOL, k = tid / NCOL;
  int js = k >> 6, v0 = k & 63;
  int j = c >> 8, r = c & 255, g = r >> 6, u0 = r & 63;
  float val = 0.f;
  if (v0 < HSL && u0 < HSL) val = W[(js * HSL + v0) * 1200 + g * 300 + j * HSL + u0];
  Wp[((k >> 3) * NCOL + c) * 8 + (k & 7)] = f2b(val);
}

__global__ void k_reorder_wx(const float* __restrict__ W, unsigned short* __restrict__ Wp) {
  int tid = blockIdx.x * 256 + threadIdx.x;
  if (tid >= KX * NCOL) return;
  int c = tid % NCOL, k = tid / NCOL;
  int j = c >> 8, r = c & 255, g = r >> 6, u0 = r & 63;
  float val = 0.f;
  if (k < 150 && u0 < HSL) val = W[k * 1200 + g * 300 + j * HSL + u0];
  Wp[((k >> 3) * NCOL + c) * 8 + (k & 7)] = f2b(val);
}

__global__ void k_reorder_b(const float* __restrict__ b, float* __restrict__ bp) {
  int c = blockIdx.x * 256 + threadIdx.x;
  if (c >= NCOL) return;
  int j = c >> 8, r = c & 255, g = r >> 6, u0 = r & 63;
  bp[c] = (u0 < HSL) ? b[g * 300 + j * HSL + u0] : 0.f;
}

__global__ void k_reorder_u(const float* __restrict__ U, unsigned short* __restrict__ Up) {
  int tid = blockIdx.x * 256 + threadIdx.x;
  if (tid >= KH * 16) return;
  int n = tid % 16, k = tid / 16;
  int js = k >> 6, v0 = k & 63;
  float v = (v0 < HSL && n < 5) ? U[(js * HSL + v0) * 5 + n] : 0.f;
  Up[((k >> 3) * 16 + n) * 8 + (k & 7)] = f2b(v);
}

// atomic-store init for flags/xcd_cnt (no dirty-line hazard)
__global__ void k_init(int* __restrict__ flags, int n, int* __restrict__ xcd_cnt) {
  int i = blockIdx.x * 256 + threadIdx.x;
  if (i < n)
    __hip_atomic_store(flags + i, 0, __ATOMIC_RELAXED, __HIP_MEMORY_SCOPE_AGENT);
  if (i < 8)
    __hip_atomic_store(xcd_cnt + i, 0, __ATOMIC_RELAXED, __HIP_MEMORY_SCOPE_AGENT);
}

__launch_bounds__(256, 1)
__global__ void k_lstm(const int* __restrict__ ids, const float* __restrict__ embed,
                       const unsigned short* __restrict__ Wp,
                       const unsigned short* __restrict__ Wxp,
                       const float* __restrict__ bp,
                       const unsigned short* __restrict__ Up,
                       unsigned short* __restrict__ hbuf,   // [3][1024][320] bf16
                       int* __restrict__ flags,             // [120][32] @128B counters
                       int* __restrict__ xcd_cnt,           // [8]
                       const float* __restrict__ b2,
                       float* __restrict__ out) {
  __shared__ __align__(16) unsigned short x_lds[2][BS * XST];
  __shared__ char lds_pad[61440];   // force 1 block/CU (total LDS > 80KB)
  __shared__ int role[2];

  const int tid = threadIdx.x;
  if (tid == 0) {
    ((volatile char*)lds_pad)[0] = 0;
    int xcd = __builtin_amdgcn_s_getreg(63508) & 7;  // HW_REG_XCC_ID
    int rank = atomicAdd(&xcd_cnt[xcd], 1);
    role[0] = xcd; role[1] = rank;
  }
  __syncthreads();
  const int xcd = role[0], rank = role[1];
  if (rank >= GH * 4) return;               // spare block
  const int bg = xcd * 4 + rank / GH;
  const int j  = rank % GH;

  const int lane = tid & 63, w = tid >> 6;
  const int l15 = lane & 15, l4 = lane >> 4;

  if (tid < BS) {
#pragma unroll
    for (int bq = 0; bq < 2; ++bq)
      for (int e = 150; e < XST; ++e) x_lds[bq][tid * XST + e] = 0;
  }

  const int colb = j * 256 + w * 16 + l15;

  // persistent B fragments -> AGPRs via "a"-constrained MFMA uses
  bf16x8 bh[10][4], bx[5][4];
#pragma unroll
  for (int kk = 0; kk < 10; ++kk)
#pragma unroll
    for (int g = 0; g < 4; ++g)
      bh[kk][g] = *(const bf16x8*)(Wp + ((kk * 4 + l4) * NCOL + colb + g * 64) * 8);
#pragma unroll
  for (int kk = 0; kk < 5; ++kk)
#pragma unroll
    for (int g = 0; g < 4; ++g)
      bx[kk][g] = *(const bf16x8*)(Wxp + ((kk * 4 + l4) * NCOL + colb + g * 64) * 8);

  float bias[4];
#pragma unroll
  for (int g = 0; g < 4; ++g) bias[g] = bp[colb + g * 64];
  const float b2v = (l15 < 5) ? b2[l15] : 0.f;

  // gather geometry for tid<192
  int xrow = 0, koff = 0, nf2 = 0, f = 0;
  const bool gth = (tid < 192);
  if (gth) {
    xrow = tid / 6; int half = tid % 6; f = half >> 1; int hh = half & 1;
    nf2 = hh ? 12 : 13;
    koff = f * 50 + (hh ? 26 : 0);
  }
  const long idbase = (long)(bg * BS + xrow) * TT * 3 + f;
  const int  eoff   = (koff - f * 50);

  // prologue: x(0) gather+pack
  if (gth) {
    int id0 = ids[idbase + 0 * 3];
    const float* src = embed + (long)id0 * 50 + eoff;
    unsigned short* dst = &x_lds[0][xrow * XST + koff];
#pragma unroll
    for (int e = 0; e < 13; ++e)
      if (e < nf2) {
        float2 v = *(const float2*)(src + 2 * e);
        *(unsigned*)(dst + 2 * e) = (unsigned)f2b(v.x) | ((unsigned)f2b(v.y) << 16);
      }
  }
  __syncthreads();

  f32x4 acc[4][2];
  float cst[2][4];
#pragma unroll
  for (int g = 0; g < 4; ++g)
#pragma unroll
    for (int mt = 0; mt < 2; ++mt) acc[g][mt] = {0.f, 0.f, 0.f, 0.f};
#pragma unroll
  for (int mt = 0; mt < 2; ++mt)
#pragma unroll
    for (int r = 0; r < 4; ++r) cst[mt][r] = 0.f;

  // GEMM1(0)
  {
    const unsigned short* xb = &x_lds[0][l15 * XST + l4 * 8];
#pragma unroll
    for (int kk = 0; kk < 5; ++kk) {
      bf16x8 a0 = *(const bf16x8*)(xb + kk * 32);
      bf16x8 a1 = *(const bf16x8*)(xb + 16 * XST + kk * 32);
#pragma unroll
      for (int g = 0; g < 4; ++g) {
        mfma_bA(a0, bx[kk][g], acc[g][0]);
        mfma_bA(a1, bx[kk][g], acc[g][1]);
      }
    }
  }

  // pipeline regs: xv = embed(t+1) floats; idv = ids(t+2)
  float2 xv[13];
  int idv = 0;
  if (gth) {
    int id1 = ids[idbase + 1 * 3];
    const float* src = embed + (long)id1 * 50 + eoff;
#pragma unroll
    for (int e = 0; e < 13; ++e)
      if (e < nf2) xv[e] = *(const float2*)(src + 2 * e);
    idv = ids[idbase + 2 * 3];
  }

  bf16x8 va0[10], va1[10];

  for (int t = 0; t < TT; ++t) {
    if (t > 0) {
      // per-wave gate: lane 0 polls (R8-proven relaxed-AGENT load), wave joins
      if (lane == 0) {
        const int* fp = flags + ((t - 1) * GB + bg) * FSTR;
        int it = 0;
        while (__hip_atomic_load(fp, __ATOMIC_RELAXED, __HIP_MEMORY_SCOPE_AGENT) < NREL) {
          if (++it > 500000) break;  // bail -> wrong answer, not a hang
        }
      }
      // per-wave: drop stale L1, then read partners' h from XCD L2 (R8-proven)
      asm volatile("buffer_inv\n\ts_waitcnt vmcnt(0)" ::: "memory");

      const unsigned short* ar =
          hbuf + ((t - 1) % NSLOT) * (BATCH * KH) + (bg * BS + l15) * KH + l4 * 8;
#pragma unroll
      for (int kk = 0; kk < 10; ++kk) {
        va0[kk] = *(const bf16x8*)(ar + kk * 32);
        va1[kk] = *(const bf16x8*)(ar + 16 * KH + kk * 32);
      }
#pragma unroll
      for (int kk = 0; kk < 10; ++kk) {
#pragma unroll
        for (int g = 0; g < 4; ++g) {
          mfma_bA(va0[kk], bh[kk][g], acc[g][0]);
          mfma_bA(va1[kk], bh[kk][g], acc[g][1]);
        }
      }
    }

    // gates + state update; h(t) packed 8B plain write-through stores -> local L2
    unsigned short* hdst = hbuf + (t % NSLOT) * (BATCH * KH);
#pragma unroll
    for (int mt = 0; mt < 2; ++mt) {
#pragma unroll
      for (int r = 0; r < 4; ++r) {
        float zi = acc[0][mt][r] + bias[0];
        float zf = acc[1][mt][r] + bias[1];
        float zg = acc[2][mt][r] + bias[2];
        float zo = acc[3][mt][r] + bias[3];
        float gi = sigm(zi), gf = sigm(zf), go = sigm(zo), gg = tanhf_(zg);
        float c = gf * cst[mt][r] + gi * gg;
        cst[mt][r] = c;
        float h = go * tanhf_(c);
        unsigned v = f2b(h);
        unsigned p1 = v | ((unsigned)__shfl_xor((int)v, 1) << 16);
        unsigned long long p2 = (unsigned long long)p1 |
            ((unsigned long long)(unsigned)__shfl_xor((int)p1, 2) << 32);
        if ((l15 & 3) == 0) {
          int row = bg * BS + mt * 16 + l4 * 4 + r;
          *(unsigned long long*)(hdst + row * KH + j * SL + w * 16 + l15) = p2;
        }
      }
      acc[0][mt] = {0.f, 0.f, 0.f, 0.f};
      acc[1][mt] = {0.f, 0.f, 0.f, 0.f};
      acc[2][mt] = {0.f, 0.f, 0.f, 0.f};
      acc[3][mt] = {0.f, 0.f, 0.f, 0.f};
    }

    // per-wave release: own stores L2-acked, then lane0 fetch_add (R8-proven op)
    asm volatile("s_waitcnt vmcnt(0)" ::: "memory");
    if (lane == 0)
      __hip_atomic_fetch_add(flags + (t * GB + bg) * FSTR, 1, __ATOMIC_RELAXED,
                             __HIP_MEMORY_SCOPE_AGENT);

    // y(t-1) duty from register A-frags (waves 2/3; post-release, off chain)
    if (t > 0 && j == (t - 1) % GH) {
      if (w == 2) {
        f32x4 ay = {0.f, 0.f, 0.f, 0.f};
#pragma unroll
        for (int kk = 0; kk < 10; ++kk) {
          bf16x8 u = *(const bf16x8*)(Up + ((kk * 4 + l4) * 16 + l15) * 8);
          ay = __builtin_amdgcn_mfma_f32_16x16x32_bf16(va0[kk], u, ay, 0, 0, 0);
        }
        if (l15 < 5)
#pragma unroll
          for (int q = 0; q < 4; ++q)
            out[((bg * BS + l4 * 4 + q) * TT + (t - 1)) * 5 + l15] = ay[q] + b2v;
      } else if (w == 3) {
        f32x4 ay = {0.f, 0.f, 0.f, 0.f};
#pragma unroll
        for (int kk = 0; kk < 10; ++kk) {
          bf16x8 u = *(const bf16x8*)(Up + ((kk * 4 + l4) * 16 + l15) * 8);
          ay = __builtin_amdgcn_mfma_f32_16x16x32_bf16(va1[kk], u, ay, 0, 0, 0);
        }
        if (l15 < 5)
#pragma unroll
          for (int q = 0; q < 4; ++q)
            out[((bg * BS + 16 + l4 * 4 + q) * TT + (t - 1)) * 5 + l15] = ay[q] + b2v;
      }
    }

    // tail: pack x(t+1); GEMM1(t+1); refill pipeline (t+2 embed, t+3 ids)
    if (t + 1 < TT) {
      if (gth) {
        unsigned short* dst = &x_lds[(t + 1) & 1][xrow * XST + koff];
#pragma unroll
        for (int e = 0; e < 13; ++e)
          if (e < nf2)
            *(unsigned*)(dst + 2 * e) = (unsigned)f2b(xv[e].x) | ((unsigned)f2b(xv[e].y) << 16);
      }
      __syncthreads();
      const unsigned short* xb = &x_lds[(t + 1) & 1][l15 * XST + l4 * 8];
#pragma unroll
      for (int kk = 0; kk < 5; ++kk) {
        bf16x8 a0 = *(const bf16x8*)(xb + kk * 32);
        bf16x8 a1 = *(const bf16x8*)(xb + 16 * XST + kk * 32);
#pragma unroll
        for (int g = 0; g < 4; ++g) {
          mfma_bA(a0, bx[kk][g], acc[g][0]);
          mfma_bA(a1, bx[kk][g], acc[g][1]);
        }
      }
      if (gth && t + 2 < TT) {
        const float* src = embed + (long)idv * 50 + eoff;
#pragma unroll
        for (int e = 0; e < 13; ++e)
          if (e < nf2) xv[e] = *(const float2*)(src + 2 * e);
        if (t + 3 < TT) idv = ids[idbase + (long)(t + 3) * 3];
      }
    }
  }

  // epilogue: y(119) by slice 4
  if (j == (TT - 1) % GH) {
    if (lane == 0) {
      const int* fp = flags + ((TT - 1) * GB + bg) * FSTR;
      int it = 0;
      while (__hip_atomic_load(fp, __ATOMIC_RELAXED, __HIP_MEMORY_SCOPE_AGENT) < NREL) {
        if (++it > 500000) break;
      }
    }
    asm volatile("buffer_inv\n\ts_waitcnt vmcnt(0)" ::: "memory");
    const unsigned short* ar =
        hbuf + ((TT - 1) % NSLOT) * (BATCH * KH) + (bg * BS + l15) * KH + l4 * 8;
#pragma unroll
    for (int kk = 0; kk < 10; ++kk) {
      va0[kk] = *(const bf16x8*)(ar + kk * 32);
      va1[kk] = *(const bf16x8*)(ar + 16 * KH + kk * 32);
    }
    if (w == 2) {
      f32x4 ay = {0.f, 0.f, 0.f, 0.f};
#pragma unroll
      for (int kk = 0; kk < 10; ++kk) {
        bf16x8 u = *(const bf16x8*)(Up + ((kk * 4 + l4) * 16 + l15) * 8);
        ay = __builtin_amdgcn_mfma_f32_16x16x32_bf16(va0[kk], u, ay, 0, 0, 0);
      }
      if (l15 < 5)
#pragma unroll
        for (int q = 0; q < 4; ++q)
          out[((bg * BS + l4 * 4 + q) * TT + (TT - 1)) * 5 + l15] = ay[q] + b2v;
    } else if (w == 3) {
      f32x4 ay = {0.f, 0.f, 0.f, 0.f};
#pragma unroll
      for (int kk = 0; kk < 10; ++kk) {
        bf16x8 u = *(const bf16x8*)(Up + ((kk * 4 + l4) * 16 + l15) * 8);
        ay = __builtin_amdgcn_mfma_f32_16x16x32_bf16(va1[kk], u, ay, 0, 0, 0);
      }
      if (l15 < 5)
#pragma unroll
        for (int q = 0; q < 4; ++q)
          out[((bg * BS + 16 + l4 * 4 + q) * TT + (TT - 1)) * 5 + l15] = ay[q] + b2v;
    }
  }
}

extern "C" void kernel_launch(void* const* d_in, const int* in_sizes, int n_in,
                              void* d_out, int out_size, void* d_ws, size_t ws_size,
                              hipStream_t stream) {
  const int*   ids   = (const int*)d_in[0];
  const float* embed = (const float*)d_in[1];
  const float* Wx    = (const float*)d_in[2];
  const float* Wh    = (const float*)d_in[3];
  const float* b     = (const float*)d_in[4];
  const float* U     = (const float*)d_in[5];
  const float* b2    = (const float*)d_in[6];
  float* out = (float*)d_out;

  char* ws = (char*)d_ws;
  size_t off = 0;
  unsigned short* Wp   = (unsigned short*)(ws + off); off += (size_t)KH * NCOL * 2;
  unsigned short* Wxp  = (unsigned short*)(ws + off); off += (size_t)KX * NCOL * 2;
  float*          bp   = (float*)(ws + off);          off += (size_t)NCOL * 4;
  unsigned short* Up   = (unsigned short*)(ws + off); off += (size_t)KH * 16 * 2;
  unsigned short* hbuf = (unsigned short*)(ws + off); off += (size_t)NSLOT * BATCH * KH * 2;
  int*            flags= (int*)(ws + off);            off += (size_t)TT * GB * FSTR * 4;
  int*            xcd_cnt = (int*)(ws + off);         off += 8 * 4;
  if (ws_size < off) return;  // ~3.7 MB required

  k_init<<<(TT * GB * FSTR + 255) / 256, 256, 0, stream>>>(flags, TT * GB * FSTR, xcd_cnt);
  k_reorder_wh<<<(KH * NCOL + 255) / 256, 256, 0, stream>>>(Wh, Wp);
  k_reorder_wx<<<(KX * NCOL + 255) / 256, 256, 0, stream>>>(Wx, Wxp);
  k_reorder_b<<<(NCOL + 255) / 256, 256, 0, stream>>>(b, bp);
  k_reorder_u<<<(KH * 16 + 255) / 256, 256, 0, stream>>>(U, Up);

  k_lstm<<<dim3(NB), dim3(256), 0, stream>>>(ids, embed, Wp, Wxp, bp, Up,
                                             hbuf, flags, xcd_cnt, b2, out);
}